// Round 9
// baseline (1213.735 us; speedup 1.0000x reference)
//
#include <hip/hip_runtime.h>

#define HIDDEN 128
#define N_RAYS 65536
#define NEAR_D 0.01f
#define FAR_D 10.0f
#define MAX_ITERS 32

typedef _Float16 f16x8 __attribute__((ext_vector_type(8)));
typedef float f32x16 __attribute__((ext_vector_type(16)));

// DPP-assisted add: v + (v shifted by CTRL). Immediate operands via template
// params (builtin requires constant integers). bound_ctrl=1 -> OOB lanes read 0.
template <int CTRL, int ROW_MASK>
__device__ __forceinline__ float dpp_add(float v) {
    int s = __builtin_amdgcn_update_dpp(0, __float_as_int(v), CTRL, ROW_MASK, 0xF, true);
    return v + __int_as_float(s);
}
// Sum over each 32-lane half; result lands in lane 31 (half 0) / lane 63 (half 1).
__device__ __forceinline__ float half_sum_dpp(float v) {
    v = dpp_add<0x111, 0xF>(v);   // row_shr:1
    v = dpp_add<0x112, 0xF>(v);   // row_shr:2
    v = dpp_add<0x114, 0xF>(v);   // row_shr:4
    v = dpp_add<0x118, 0xF>(v);   // row_shr:8  -> lanes 15/31/47/63 hold row16 sums
    v = dpp_add<0x142, 0xA>(v);   // row_bcast15 into rows 1,3 -> lanes 31/63 hold 32-sums
    return v;
}

// ---------------------------------------------------------------------------
// Prologue: W2 B-operand fragment image (fp16 hi limb | lo limb).
//   img[l*16384 + (t*8+c)*512 + L*8 + j] == limb_l( W2[k][n] ),
//   n = t*32 + (L&31),  k = c*16 + ((L>>5)&1)*8 + j.
// ---------------------------------------------------------------------------
__global__ void w2_frag_kernel(const float* __restrict__ W2,
                               _Float16* __restrict__ img) {
    int tid = blockIdx.x * blockDim.x + threadIdx.x;   // 0..16383
    int j = tid & 7;
    int L = (tid >> 3) & 63;
    int tc = tid >> 9;
    int t = tc >> 3, c = tc & 7;
    int n = t * 32 + (L & 31);
    int k = c * 16 + ((L >> 5) & 1) * 8 + j;
    float w = W2[k * HIDDEN + n];
    _Float16 hi = (_Float16)w;
    _Float16 lo = (_Float16)(w - (float)hi);
    img[tid] = hi;
    img[16384 + tid] = lo;
}

// ---------------------------------------------------------------------------
// Block = 256 threads = 4 independent waves, 32 rays/wave, MFMA layer-2.
// R8/R9 vs R7: tile-0 B-frags held in regs (−16 LDS reads/iter), fully-
// unrolled chunk loop, and the 32-lane layer-3 reduction moved from
// ds_bpermute butterfly (80 DS ops) to DPP adds on the VALU pipe.
// ---------------------------------------------------------------------------
__launch_bounds__(256, 2)
__global__ void sphere_trace_kernel(
    const float* __restrict__ origins,
    const float* __restrict__ directions,
    const float* __restrict__ W1,    // [3][128]
    const float* __restrict__ b1,    // [128]
    const _Float16* __restrict__ w2img, // 32768 halfs (hi | lo)
    const float* __restrict__ b2,    // [128]
    const float* __restrict__ W3,    // [128]
    const float* __restrict__ b3,    // [1]
    const float* __restrict__ Wc1,   // [3][128]
    const float* __restrict__ bc1,   // [128]
    const float* __restrict__ Wc2,   // [128][3]
    const float* __restrict__ bc2,   // [3]
    float* __restrict__ out)         // [N][3]
{
    __shared__ __align__(16) _Float16 wlds[32768];   // 64 KB fragment image
    __shared__ float sbuf[4][32];                    // per-wave s exchange

    const int tid = threadIdx.x;
    const int lane = tid & 63;
    const int w = __builtin_amdgcn_readfirstlane(tid >> 6);
    const int q = lane >> 5;           // half-wave id
    const int n32 = lane & 31;         // N-column within tile / ray id

    // ---- stage fragment image into LDS (only __syncthreads in the kernel)
    {
        const float4* src = (const float4*)w2img;
        float4* dst = (float4*)wlds;
        #pragma unroll
        for (int i = 0; i < 16; ++i)
            dst[tid + 256 * i] = src[tid + 256 * i];
    }
    __syncthreads();

    // ---- tile-0 B-fragments held in registers for the whole kernel
    f16x8 B0h[8], B0l[8];
    #pragma unroll
    for (int c = 0; c < 8; ++c) {
        B0h[c] = *(const f16x8*)(wlds + (c << 9) + (lane << 3));
        B0l[c] = *(const f16x8*)(wlds + 16384 + (c << 9) + (lane << 3));
    }

    // ---- analytic layer-1 magnitude bound constants (once per wave)
    float bAx, bAy, bAz, bB;
    {
        bAx = fmaxf(fabsf(W1[lane]),              fabsf(W1[lane + 64]));
        bAy = fmaxf(fabsf(W1[HIDDEN + lane]),     fabsf(W1[HIDDEN + lane + 64]));
        bAz = fmaxf(fabsf(W1[2 * HIDDEN + lane]), fabsf(W1[2 * HIDDEN + lane + 64]));
        bB  = fmaxf(fabsf(b1[lane]),              fabsf(b1[lane + 64]));
        #pragma unroll
        for (int m = 1; m < 64; m <<= 1) {
            bAx = fmaxf(bAx, __shfl_xor(bAx, m));
            bAy = fmaxf(bAy, __shfl_xor(bAy, m));
            bAz = fmaxf(bAz, __shfl_xor(bAz, m));
            bB  = fmaxf(bB,  __shfl_xor(bB,  m));
        }
    }

    // ---- ray state (owner lanes 0..31)
    const int ray = blockIdx.x * 128 + w * 32 + n32;
    float px = 0.f, py = 0.f, pz = 0.f, dx = 0.f, dy = 0.f, dz = 0.f;
    float dist = 0.0f;
    bool frozen = true;
    if (lane < 32) {
        px = origins[ray * 3 + 0];
        py = origins[ray * 3 + 1];
        pz = origins[ray * 3 + 2];
        dx = directions[ray * 3 + 0];
        dy = directions[ray * 3 + 1];
        dz = directions[ray * 3 + 2];
        frozen = false;
    }

    // ---- per-lane epilogue constants (4 output columns n = t*32 + n32)
    float b2v[4], w3v[4];
    #pragma unroll
    for (int t = 0; t < 4; ++t) {
        b2v[t] = b2[t * 32 + n32];
        w3v[t] = W3[t * 32 + n32];
    }
    const float b3v = b3[0];
    const int q8 = q * 8;

    #pragma unroll 1
    for (int it = 0; it < MAX_ITERS; ++it) {
        // broadcast ray n32's position to all lanes
        const float ppx = __shfl(px, n32);
        const float ppy = __shfl(py, n32);
        const float ppz = __shfl(pz, n32);

        // ---- analytic pow2 scale (bound >= true max of h for this ray)
        const float bound = fmaf(fabsf(ppx), bAx, fmaf(fabsf(ppy), bAy,
                            fmaf(fabsf(ppz), bAz, bB)));
        float sc = 1.0f, inv = 1.0f;
        {
            const int e = (int)((__float_as_uint(bound) >> 23) & 255u);
            if (e > 137) {
                const int sh = e - 137;
                sc  = __uint_as_float((unsigned)(127 - sh) << 23);
                inv = __uint_as_float((unsigned)(127 + sh) << 23);
            }
        }

        // ---- layer 2: chunk-outer (fully unrolled), Ah/Al transient per chunk
        f32x16 acc[4];
        #pragma unroll
        for (int t = 0; t < 4; ++t)
            #pragma unroll
            for (int r = 0; r < 16; ++r) acc[t][r] = 0.0f;

        #pragma unroll
        for (int c = 0; c < 8; ++c) {
            // layer 1 for this chunk's 8 k-values, fused f16 hi/lo split
            f16x8 Ah, Al;
            {
                const int kb = c * 16 + q8;
                const float* wpx = W1 + kb;
                const float* wpy = W1 + HIDDEN + kb;
                const float* wpz = W1 + 2 * HIDDEN + kb;
                const float* bp  = b1 + kb;
                #pragma unroll
                for (int jj = 0; jj < 8; ++jj) {
                    const float hv = fmaxf(
                        fmaf(ppx, wpx[jj], fmaf(ppy, wpy[jj],
                        fmaf(ppz, wpz[jj], bp[jj]))), 0.0f);
                    const float x = hv * sc;               // exact (pow2)
                    const _Float16 hi = (_Float16)x;
                    Ah[jj] = hi;
                    Al[jj] = (_Float16)(x - (float)hi);
                }
            }
            // tile 0 from registers
            acc[0] = __builtin_amdgcn_mfma_f32_32x32x16_f16(Ah, B0h[c], acc[0], 0, 0, 0);
            acc[0] = __builtin_amdgcn_mfma_f32_32x32x16_f16(Ah, B0l[c], acc[0], 0, 0, 0);
            acc[0] = __builtin_amdgcn_mfma_f32_32x32x16_f16(Al, B0h[c], acc[0], 0, 0, 0);
            // tiles 1..3 from LDS
            #pragma unroll
            for (int t = 1; t < 4; ++t) {
                const int off = ((t * 8 + c) << 9) + (lane << 3);
                const f16x8 bh = *(const f16x8*)(wlds + off);
                const f16x8 bl = *(const f16x8*)(wlds + 16384 + off);
                acc[t] = __builtin_amdgcn_mfma_f32_32x32x16_f16(Ah, bh, acc[t], 0, 0, 0);
                acc[t] = __builtin_amdgcn_mfma_f32_32x32x16_f16(Ah, bl, acc[t], 0, 0, 0);
                acc[t] = __builtin_amdgcn_mfma_f32_32x32x16_f16(Al, bh, acc[t], 0, 0, 0);
            }
        }

        // ---- epilogue: per-C-row inverse scales, bias, relu, dot W3
        float invr[16];
        #pragma unroll
        for (int r = 0; r < 16; ++r) {
            const int msrc = (r & 3) + 8 * (r >> 2) + 4 * q;
            invr[r] = __shfl(inv, msrc);
        }
        float ps[16];
        #pragma unroll
        for (int r = 0; r < 16; ++r) ps[r] = 0.0f;
        #pragma unroll
        for (int t = 0; t < 4; ++t) {
            #pragma unroll
            for (int r = 0; r < 16; ++r) {
                const float v = fmaxf(fmaf(acc[t][r], invr[r], b2v[t]), 0.0f);
                ps[r] = fmaf(v, w3v[t], ps[r]);
            }
        }

        // ---- 32-lane reduction on the VALU pipe (DPP); sums land in lanes 31/63
        #pragma unroll
        for (int r = 0; r < 16; ++r)
            ps[r] = half_sum_dpp(ps[r]);
        if ((lane & 31) == 31) {
            const int mb = q * 4;      // q=0 -> rows m, q=1 -> rows m+4
            #pragma unroll
            for (int g = 0; g < 4; ++g) {
                float4 v4;
                v4.x = ps[4 * g + 0];  // row 8g+0+mb
                v4.y = ps[4 * g + 1];
                v4.z = ps[4 * g + 2];
                v4.w = ps[4 * g + 3];
                *(float4*)&sbuf[w][8 * g + mb] = v4;
            }
        }
        float s = 0.0f;
        if (lane < 32) s = sbuf[w][lane] + b3v;

        // ---- march (exact reference semantics) on owner lanes
        if (lane < 32) {
            const bool valid = (s <= NEAR_D) && (dist < FAR_D);
            if (!frozen) {
                if (valid) {
                    frozen = true;
                } else {
                    dist += s;
                    px = fmaf(dx, s, px);
                    py = fmaf(dy, s, py);
                    pz = fmaf(dz, s, pz);
                }
            }
        }
        if (__ballot((lane < 32) && !frozen) == 0) break;
    }

    // ---- color MLP (once): lane owns hidden units lane, lane+64
    const int k0 = lane, k1 = lane + 64;
    const float cx0 = Wc1[k0], cx1 = Wc1[k1];
    const float cy0 = Wc1[HIDDEN + k0], cy1 = Wc1[HIDDEN + k1];
    const float cz0 = Wc1[2 * HIDDEN + k0], cz1 = Wc1[2 * HIDDEN + k1];
    const float cb0 = bc1[k0], cb1 = bc1[k1];
    const float u00 = Wc2[k0 * 3 + 0], u01 = Wc2[k0 * 3 + 1], u02 = Wc2[k0 * 3 + 2];
    const float u10 = Wc2[k1 * 3 + 0], u11 = Wc2[k1 * 3 + 1], u12 = Wc2[k1 * 3 + 2];

    float g0 = 0.f, g1 = 0.f, g2 = 0.f;
    #pragma unroll 1
    for (int m = 0; m < 32; ++m) {
        const float qx = __shfl(px, m);
        const float qy = __shfl(py, m);
        const float qz = __shfl(pz, m);
        const float h0 = fmaxf(fmaf(qx, cx0, fmaf(qy, cy0, fmaf(qz, cz0, cb0))), 0.f);
        const float h1 = fmaxf(fmaf(qx, cx1, fmaf(qy, cy1, fmaf(qz, cz1, cb1))), 0.f);
        float a0 = fmaf(h0, u00, h1 * u10);
        float a1 = fmaf(h0, u01, h1 * u11);
        float a2 = fmaf(h0, u02, h1 * u12);
        #pragma unroll
        for (int mask = 1; mask < 64; mask <<= 1) {
            a0 += __shfl_xor(a0, mask);
            a1 += __shfl_xor(a1, mask);
            a2 += __shfl_xor(a2, mask);
        }
        if (lane == m) { g0 = a0; g1 = a1; g2 = a2; }
    }

    if (lane < 32) {
        float c0 = 0.f, c1 = 0.f, c2 = 0.f;
        if (frozen || dist < FAR_D) {
            c0 = 1.0f / (1.0f + __expf(-(g0 + bc2[0])));
            c1 = 1.0f / (1.0f + __expf(-(g1 + bc2[1])));
            c2 = 1.0f / (1.0f + __expf(-(g2 + bc2[2])));
        }
        out[ray * 3 + 0] = c0;
        out[ray * 3 + 1] = c1;
        out[ray * 3 + 2] = c2;
    }
}

extern "C" void kernel_launch(void* const* d_in, const int* in_sizes, int n_in,
                              void* d_out, int out_size, void* d_ws, size_t ws_size,
                              hipStream_t stream) {
    const float* origins    = (const float*)d_in[0];
    const float* directions = (const float*)d_in[1];
    const float* W1  = (const float*)d_in[2];
    const float* b1  = (const float*)d_in[3];
    const float* W2  = (const float*)d_in[4];
    const float* b2  = (const float*)d_in[5];
    const float* W3  = (const float*)d_in[6];
    const float* b3  = (const float*)d_in[7];
    const float* Wc1 = (const float*)d_in[8];
    const float* bc1 = (const float*)d_in[9];
    const float* Wc2 = (const float*)d_in[10];
    const float* bc2 = (const float*)d_in[11];
    float* out = (float*)d_out;

    _Float16* w2img = (_Float16*)d_ws;   // 64 KB fragment image

    w2_frag_kernel<<<64, 256, 0, stream>>>(W2, w2img);

    sphere_trace_kernel<<<N_RAYS / 128, 256, 0, stream>>>(
        origins, directions, W1, b1, w2img, b2, W3, b3,
        Wc1, bc1, Wc2, bc2, out);
}

// Round 10
// 306.208 us; speedup vs baseline: 3.9638x; 3.9638x over previous
//
#include <hip/hip_runtime.h>

#define HIDDEN 128
#define N_RAYS 65536
#define NEAR_D 0.01f
#define FAR_D 10.0f
#define MAX_ITERS 32

typedef _Float16 f16x8 __attribute__((ext_vector_type(8)));
typedef float f32x16 __attribute__((ext_vector_type(16)));

// DPP-assisted add: v + (v shifted by CTRL). Immediates via template params.
// bound_ctrl=1 -> out-of-bounds source lanes contribute 0.
template <int CTRL, int ROW_MASK>
__device__ __forceinline__ float dpp_add(float v) {
    int s = __builtin_amdgcn_update_dpp(0, __float_as_int(v), CTRL, ROW_MASK, 0xF, true);
    return v + __int_as_float(s);
}
// Sum over each 32-lane half; result lands in lane 31 (half 0) / lane 63 (half 1).
__device__ __forceinline__ float half_sum_dpp(float v) {
    v = dpp_add<0x111, 0xF>(v);   // row_shr:1
    v = dpp_add<0x112, 0xF>(v);   // row_shr:2
    v = dpp_add<0x114, 0xF>(v);   // row_shr:4
    v = dpp_add<0x118, 0xF>(v);   // row_shr:8  -> lanes 15/31/47/63 hold 16-sums
    v = dpp_add<0x142, 0xA>(v);   // row_bcast15 -> lanes 31/63 hold 32-sums
    return v;
}

// ---------------------------------------------------------------------------
// Prologue: W2 B-operand fragment image (fp16 hi limb | lo limb).
//   img[l*16384 + (t*8+c)*512 + L*8 + j] == limb_l( W2[k][n] ),
//   n = t*32 + (L&31),  k = c*16 + ((L>>5)&1)*8 + j.
// ---------------------------------------------------------------------------
__global__ void w2_frag_kernel(const float* __restrict__ W2,
                               _Float16* __restrict__ img) {
    int tid = blockIdx.x * blockDim.x + threadIdx.x;   // 0..16383
    int j = tid & 7;
    int L = (tid >> 3) & 63;
    int tc = tid >> 9;
    int t = tc >> 3, c = tc & 7;
    int n = t * 32 + (L & 31);
    int k = c * 16 + ((L >> 5) & 1) * 8 + j;
    float w = W2[k * HIDDEN + n];
    _Float16 hi = (_Float16)w;
    _Float16 lo = (_Float16)(w - (float)hi);
    img[tid] = hi;
    img[16384 + tid] = lo;
}

// ---------------------------------------------------------------------------
// Block = 256 threads = 4 independent waves, 32 rays/wave, MFMA layer-2.
// R10 = R7 structure EXACTLY (chunk-outer `#pragma unroll 1`, all B-frags
// from LDS — register-lean, VGPR 88, no spill) + ONE register-neutral change:
// layer-3 32-lane reduction moved from ds_bpermute butterfly to DPP adds.
// (R8/R9's reg-held tile-0 B-frags = 64 VGPRs -> spills -> 3.1 GB FETCH. No.)
// ---------------------------------------------------------------------------
__launch_bounds__(256, 2)
__global__ void sphere_trace_kernel(
    const float* __restrict__ origins,
    const float* __restrict__ directions,
    const float* __restrict__ W1,    // [3][128]
    const float* __restrict__ b1,    // [128]
    const _Float16* __restrict__ w2img, // 32768 halfs (hi | lo)
    const float* __restrict__ b2,    // [128]
    const float* __restrict__ W3,    // [128]
    const float* __restrict__ b3,    // [1]
    const float* __restrict__ Wc1,   // [3][128]
    const float* __restrict__ bc1,   // [128]
    const float* __restrict__ Wc2,   // [128][3]
    const float* __restrict__ bc2,   // [3]
    float* __restrict__ out)         // [N][3]
{
    __shared__ __align__(16) _Float16 wlds[32768];   // 64 KB fragment image
    __shared__ float sbuf[4][32];                    // per-wave s exchange

    const int tid = threadIdx.x;
    const int lane = tid & 63;
    const int w = __builtin_amdgcn_readfirstlane(tid >> 6);
    const int q = lane >> 5;           // half-wave id
    const int n32 = lane & 31;         // N-column within tile / ray id

    // ---- stage fragment image into LDS (only __syncthreads in the kernel)
    {
        const float4* src = (const float4*)w2img;
        float4* dst = (float4*)wlds;
        #pragma unroll
        for (int i = 0; i < 16; ++i)
            dst[tid + 256 * i] = src[tid + 256 * i];
    }
    __syncthreads();

    // ---- analytic layer-1 magnitude bound constants (once per wave)
    float bAx, bAy, bAz, bB;
    {
        bAx = fmaxf(fabsf(W1[lane]),              fabsf(W1[lane + 64]));
        bAy = fmaxf(fabsf(W1[HIDDEN + lane]),     fabsf(W1[HIDDEN + lane + 64]));
        bAz = fmaxf(fabsf(W1[2 * HIDDEN + lane]), fabsf(W1[2 * HIDDEN + lane + 64]));
        bB  = fmaxf(fabsf(b1[lane]),              fabsf(b1[lane + 64]));
        #pragma unroll
        for (int m = 1; m < 64; m <<= 1) {
            bAx = fmaxf(bAx, __shfl_xor(bAx, m));
            bAy = fmaxf(bAy, __shfl_xor(bAy, m));
            bAz = fmaxf(bAz, __shfl_xor(bAz, m));
            bB  = fmaxf(bB,  __shfl_xor(bB,  m));
        }
    }

    // ---- ray state (owner lanes 0..31)
    const int ray = blockIdx.x * 128 + w * 32 + n32;
    float px = 0.f, py = 0.f, pz = 0.f, dx = 0.f, dy = 0.f, dz = 0.f;
    float dist = 0.0f;
    bool frozen = true;
    if (lane < 32) {
        px = origins[ray * 3 + 0];
        py = origins[ray * 3 + 1];
        pz = origins[ray * 3 + 2];
        dx = directions[ray * 3 + 0];
        dy = directions[ray * 3 + 1];
        dz = directions[ray * 3 + 2];
        frozen = false;
    }

    // ---- per-lane epilogue constants (4 output columns n = t*32 + n32)
    float b2v[4], w3v[4];
    #pragma unroll
    for (int t = 0; t < 4; ++t) {
        b2v[t] = b2[t * 32 + n32];
        w3v[t] = W3[t * 32 + n32];
    }
    const float b3v = b3[0];
    const int q8 = q * 8;

    #pragma unroll 1
    for (int it = 0; it < MAX_ITERS; ++it) {
        // broadcast ray n32's position to all lanes
        const float ppx = __shfl(px, n32);
        const float ppy = __shfl(py, n32);
        const float ppz = __shfl(pz, n32);

        // ---- analytic pow2 scale (bound >= true max of h for this ray)
        const float bound = fmaf(fabsf(ppx), bAx, fmaf(fabsf(ppy), bAy,
                            fmaf(fabsf(ppz), bAz, bB)));
        float sc = 1.0f, inv = 1.0f;
        {
            const int e = (int)((__float_as_uint(bound) >> 23) & 255u);
            if (e > 137) {
                const int sh = e - 137;
                sc  = __uint_as_float((unsigned)(127 - sh) << 23);
                inv = __uint_as_float((unsigned)(127 + sh) << 23);
            }
        }

        // ---- layer 2: CHUNK-OUTER. Ah/Al transient per chunk; acc[4] live.
        f32x16 acc[4];
        #pragma unroll
        for (int t = 0; t < 4; ++t)
            #pragma unroll
            for (int r = 0; r < 16; ++r) acc[t][r] = 0.0f;

        #pragma unroll 1
        for (int c = 0; c < 8; ++c) {
            // layer 1 for this chunk's 8 k-values, fused f16 hi/lo split
            f16x8 Ah, Al;
            {
                const int kb = c * 16 + q8;
                const float* wpx = W1 + kb;
                const float* wpy = W1 + HIDDEN + kb;
                const float* wpz = W1 + 2 * HIDDEN + kb;
                const float* bp  = b1 + kb;
                #pragma unroll
                for (int jj = 0; jj < 8; ++jj) {
                    const float hv = fmaxf(
                        fmaf(ppx, wpx[jj], fmaf(ppy, wpy[jj],
                        fmaf(ppz, wpz[jj], bp[jj]))), 0.0f);
                    const float x = hv * sc;               // exact (pow2)
                    const _Float16 hi = (_Float16)x;
                    Ah[jj] = hi;
                    Al[jj] = (_Float16)(x - (float)hi);
                }
            }
            // feed all 4 N-tiles while Ah/Al are hot (B-frags from LDS)
            #pragma unroll
            for (int t = 0; t < 4; ++t) {
                const int off = ((t * 8 + c) << 9) + (lane << 3);
                const f16x8 bh = *(const f16x8*)(wlds + off);
                const f16x8 bl = *(const f16x8*)(wlds + 16384 + off);
                acc[t] = __builtin_amdgcn_mfma_f32_32x32x16_f16(Ah, bh, acc[t], 0, 0, 0);
                acc[t] = __builtin_amdgcn_mfma_f32_32x32x16_f16(Ah, bl, acc[t], 0, 0, 0);
                acc[t] = __builtin_amdgcn_mfma_f32_32x32x16_f16(Al, bh, acc[t], 0, 0, 0);
            }
        }

        // ---- epilogue: per-C-row inverse scales, bias, relu, dot W3
        float invr[16];
        #pragma unroll
        for (int r = 0; r < 16; ++r) {
            const int msrc = (r & 3) + 8 * (r >> 2) + 4 * q;
            invr[r] = __shfl(inv, msrc);
        }
        float ps[16];
        #pragma unroll
        for (int r = 0; r < 16; ++r) ps[r] = 0.0f;
        #pragma unroll
        for (int t = 0; t < 4; ++t) {
            #pragma unroll
            for (int r = 0; r < 16; ++r) {
                const float v = fmaxf(fmaf(acc[t][r], invr[r], b2v[t]), 0.0f);
                ps[r] = fmaf(v, w3v[t], ps[r]);
            }
        }

        // ---- 32-lane reduction on the VALU pipe (DPP); sums land in lanes 31/63
        #pragma unroll
        for (int r = 0; r < 16; ++r)
            ps[r] = half_sum_dpp(ps[r]);
        if ((lane & 31) == 31) {
            const int mb = q * 4;      // q=0 -> rows 8g..8g+3; q=1 -> rows 8g+4..8g+7
            #pragma unroll
            for (int g = 0; g < 4; ++g) {
                float4 v4;
                v4.x = ps[4 * g + 0];
                v4.y = ps[4 * g + 1];
                v4.z = ps[4 * g + 2];
                v4.w = ps[4 * g + 3];
                *(float4*)&sbuf[w][8 * g + mb] = v4;
            }
        }
        float s = 0.0f;
        if (lane < 32) s = sbuf[w][lane] + b3v;

        // ---- march (exact reference semantics) on owner lanes
        if (lane < 32) {
            const bool valid = (s <= NEAR_D) && (dist < FAR_D);
            if (!frozen) {
                if (valid) {
                    frozen = true;
                } else {
                    dist += s;
                    px = fmaf(dx, s, px);
                    py = fmaf(dy, s, py);
                    pz = fmaf(dz, s, pz);
                }
            }
        }
        if (__ballot((lane < 32) && !frozen) == 0) break;
    }

    // ---- color MLP (once): lane owns hidden units lane, lane+64
    const int k0 = lane, k1 = lane + 64;
    const float cx0 = Wc1[k0], cx1 = Wc1[k1];
    const float cy0 = Wc1[HIDDEN + k0], cy1 = Wc1[HIDDEN + k1];
    const float cz0 = Wc1[2 * HIDDEN + k0], cz1 = Wc1[2 * HIDDEN + k1];
    const float cb0 = bc1[k0], cb1 = bc1[k1];
    const float u00 = Wc2[k0 * 3 + 0], u01 = Wc2[k0 * 3 + 1], u02 = Wc2[k0 * 3 + 2];
    const float u10 = Wc2[k1 * 3 + 0], u11 = Wc2[k1 * 3 + 1], u12 = Wc2[k1 * 3 + 2];

    float g0 = 0.f, g1 = 0.f, g2 = 0.f;
    #pragma unroll 1
    for (int m = 0; m < 32; ++m) {
        const float qx = __shfl(px, m);
        const float qy = __shfl(py, m);
        const float qz = __shfl(pz, m);
        const float h0 = fmaxf(fmaf(qx, cx0, fmaf(qy, cy0, fmaf(qz, cz0, cb0))), 0.f);
        const float h1 = fmaxf(fmaf(qx, cx1, fmaf(qy, cy1, fmaf(qz, cz1, cb1))), 0.f);
        float a0 = fmaf(h0, u00, h1 * u10);
        float a1 = fmaf(h0, u01, h1 * u11);
        float a2 = fmaf(h0, u02, h1 * u12);
        #pragma unroll
        for (int mask = 1; mask < 64; mask <<= 1) {
            a0 += __shfl_xor(a0, mask);
            a1 += __shfl_xor(a1, mask);
            a2 += __shfl_xor(a2, mask);
        }
        if (lane == m) { g0 = a0; g1 = a1; g2 = a2; }
    }

    if (lane < 32) {
        float c0 = 0.f, c1 = 0.f, c2 = 0.f;
        if (frozen || dist < FAR_D) {
            c0 = 1.0f / (1.0f + __expf(-(g0 + bc2[0])));
            c1 = 1.0f / (1.0f + __expf(-(g1 + bc2[1])));
            c2 = 1.0f / (1.0f + __expf(-(g2 + bc2[2])));
        }
        out[ray * 3 + 0] = c0;
        out[ray * 3 + 1] = c1;
        out[ray * 3 + 2] = c2;
    }
}

extern "C" void kernel_launch(void* const* d_in, const int* in_sizes, int n_in,
                              void* d_out, int out_size, void* d_ws, size_t ws_size,
                              hipStream_t stream) {
    const float* origins    = (const float*)d_in[0];
    const float* directions = (const float*)d_in[1];
    const float* W1  = (const float*)d_in[2];
    const float* b1  = (const float*)d_in[3];
    const float* W2  = (const float*)d_in[4];
    const float* b2  = (const float*)d_in[5];
    const float* W3  = (const float*)d_in[6];
    const float* b3  = (const float*)d_in[7];
    const float* Wc1 = (const float*)d_in[8];
    const float* bc1 = (const float*)d_in[9];
    const float* Wc2 = (const float*)d_in[10];
    const float* bc2 = (const float*)d_in[11];
    float* out = (float*)d_out;

    _Float16* w2img = (_Float16*)d_ws;   // 64 KB fragment image

    w2_frag_kernel<<<64, 256, 0, stream>>>(W2, w2img);

    sphere_trace_kernel<<<N_RAYS / 128, 256, 0, stream>>>(
        origins, directions, W1, b1, w2img, b2, W3, b3,
        Wc1, bc1, Wc2, bc2, out);
}